// Round 6
// baseline (35386.453 us; speedup 1.0000x reference)
//
#include <hip/hip_runtime.h>
#include <hip/hip_fp16.h>
#include <hip/hip_cooperative_groups.h>

namespace cg = cooperative_groups;

// Problem constants: B=256, T=256, M=512, P=512
typedef _Float16 h4 __attribute__((ext_vector_type(4)));
typedef _Float16 h8 __attribute__((ext_vector_type(8)));
typedef float    f4 __attribute__((ext_vector_type(4)));

#define SC2LOG2E 2.8853900817779268f   // 2 * log2(e)

// native exp2 / rcp (v_exp_f32 IS exp2)
__device__ __forceinline__ float v_exp2(float x) { float r; asm("v_exp_f32 %0, %1" : "=v"(r) : "v"(x)); return r; }
__device__ __forceinline__ float v_rcp (float x) { float r; asm("v_rcp_f32 %0, %1" : "=v"(r) : "v"(x)); return r; }
__device__ __forceinline__ float fast_tanh(float x) {
    float e = __expf(2.0f * x);
    return 1.0f - 2.0f * v_rcp(e + 1.0f);
}
__device__ __forceinline__ float fast_sigmoid(float x) {
    return v_rcp(1.0f + __expf(-x));
}

// ---------------------------------------------------------------------------
__global__ void convert_f16(const float* __restrict__ s, _Float16* __restrict__ d, int n) {
    int i = (blockIdx.x * 256 + threadIdx.x) * 4;
    if (i < n) {
        float4 v = *(const float4*)(s + i);
        h4 o = {(_Float16)v.x, (_Float16)v.y, (_Float16)v.z, (_Float16)v.w};
        *(h4*)(d + i) = o;
    }
}

// ---------------------------------------------------------------------------
// Wg[(p<<2)|g][k] = f16( k<512 ? Wih[g*512+p][k] : Whh[g*512+p][k-512] )
__global__ void build_wg(const float* __restrict__ Wih, const float* __restrict__ Whh,
                         _Float16* __restrict__ Wg) {
    int idx = (blockIdx.x * 256 + threadIdx.x) * 4;    // over 2048*1024
    int np = idx >> 10, k = idx & 1023;
    int p = np >> 2, g = np & 3, row = g * 512 + p;
    const float* src = (k < 512) ? Wih + (size_t)row * 512 + k
                                 : Whh + (size_t)row * 512 + (k - 512);
    float4 v = *(const float4*)src;
    h4 o = {(_Float16)v.x, (_Float16)v.y, (_Float16)v.z, (_Float16)v.w};
    *(h4*)(Wg + idx) = o;
}

__global__ void build_bsum(const float* __restrict__ bih, const float* __restrict__ bhh,
                           float* __restrict__ bsum) {
    int np = blockIdx.x * 256 + threadIdx.x;  // 2048
    int p = np >> 2, g = np & 3, row = g * 512 + p;
    bsum[np] = bih[row] + bhh[row];
}

// ---------------------------------------------------------------------------
__global__ void init_state(const float* __restrict__ d0, const float* __restrict__ s0,
                           float* __restrict__ sbuf,
                           _Float16* __restrict__ qA, _Float16* __restrict__ ds) {
    int i = blockIdx.x * 256 + threadIdx.x;   // 512 x 256 = 131072
    float dv = d0[i], sv = s0[i];
    sbuf[i] = sv;
    int b = i >> 9, j = i & 511;
    qA[(size_t)b * 1024 + 512 + j] = (_Float16)dv;
    ds[(size_t)b * 1024 + j]       = (_Float16)dv;
    ds[(size_t)b * 1024 + 512 + j] = (_Float16)sv;
}

// ---------------------------------------------------------------------------
// UH2[r,n] = f16( 2log2e * sum_k H[r,k]*Ud[n,k] )  via MFMA, inline f32->f16.
// grid 1024 (m-tiles of 64), 128 threads (2 waves); n-loop inside (Ud L2-resident).
__global__ __launch_bounds__(128) void uh_mfma(const float* __restrict__ H,
                                               const float* __restrict__ Ud,
                                               _Float16* __restrict__ UH2) {
    int tid = threadIdx.x;
    int lane = tid & 63, w = tid >> 6;
    int ln = lane & 15, quad = lane >> 4;
    int m0 = blockIdx.x * 64;
    const float* arow = H + (size_t)(m0 + ln) * 512 + quad * 8;
    for (int n0 = 0; n0 < 512; n0 += 32) {
        f4 z = {0.f, 0.f, 0.f, 0.f};
        f4 acc[4] = {z, z, z, z};
        const float* brow = Ud + (size_t)(n0 + w * 16 + ln) * 512 + quad * 8;
#pragma unroll 2
        for (int k = 0; k < 16; k++) {
            float4 bx = *(const float4*)(brow + k * 32);
            float4 by = *(const float4*)(brow + k * 32 + 4);
            h8 b = {(_Float16)bx.x, (_Float16)bx.y, (_Float16)bx.z, (_Float16)bx.w,
                    (_Float16)by.x, (_Float16)by.y, (_Float16)by.z, (_Float16)by.w};
#pragma unroll
            for (int mt = 0; mt < 4; mt++) {
                const float* ap = arow + (size_t)mt * 16 * 512 + k * 32;
                float4 ax = *(const float4*)ap;
                float4 ay = *(const float4*)(ap + 4);
                h8 a = {(_Float16)ax.x, (_Float16)ax.y, (_Float16)ax.z, (_Float16)ax.w,
                        (_Float16)ay.x, (_Float16)ay.y, (_Float16)ay.z, (_Float16)ay.w};
                acc[mt] = __builtin_amdgcn_mfma_f32_16x16x32_f16(a, b, acc[mt], 0, 0, 0);
            }
        }
#pragma unroll
        for (int mt = 0; mt < 4; mt++)
#pragma unroll
            for (int r = 0; r < 4; r++)
                UH2[(size_t)(m0 + mt * 16 + quad * 4 + r) * 512 + n0 + w * 16 + ln] =
                    (_Float16)(acc[mt][r] * SC2LOG2E);
    }
}

// ---------------------------------------------------------------------------
// Persistent fused loop: 256 blocks x 1024 threads, cooperative launch.
// Per step: wq phase | grid.sync | attn phase | grid.sync | gates phase | grid.sync
__global__ __launch_bounds__(1024, 4) void fused_loop(
        const _Float16* __restrict__ UH2, const _Float16* Hh,
        const float* __restrict__ Hf, const float* __restrict__ vd,
        const _Float16* __restrict__ Wdh, const _Float16* __restrict__ Wg,
        const float* __restrict__ bsum, float* __restrict__ wq2,
        _Float16* qA, _Float16* qB, _Float16* ds,
        float* __restrict__ sbuf, float* __restrict__ attn_out,
        float* __restrict__ out) {
    cg::grid_group grid = cg::this_grid();
    __shared__ union {
        float wqp[4][256];
        struct { float es[256]; float red[4]; float red2[4]; float part[8][512]; } at;
        float gt[2][64][36];
    } sm;

    const int bid = blockIdx.x;
    const int tid = threadIdx.x;
    const int lane = tid & 63, w = tid >> 6;
    const int ln = lane & 15, quad = lane >> 4;

    for (int t = 0; t < 256; ++t) {
        _Float16* qcur = (t & 1) ? qB : qA;
        _Float16* qnxt = (t & 1) ? qA : qB;

        // ---------------- wq phase: tiles 2*bid, 2*bid+1 (16x16, K=1024, 2-way k-split)
        if (w < 4) {
            int pair = w >> 1, kh = w & 1;
            int tau = 2 * bid + pair;
            int m0 = (tau & 15) * 16, n0 = (tau >> 4) * 16;
            f4 acc = {0.f, 0.f, 0.f, 0.f};
            const h8* ap = (const h8*)(ds  + (size_t)(m0 + ln) * 1024) + kh * 64 + quad;
            const h8* bp = (const h8*)(Wdh + (size_t)(n0 + ln) * 1024) + kh * 64 + quad;
#pragma unroll
            for (int k = 0; k < 16; k++)
                acc = __builtin_amdgcn_mfma_f32_16x16x32_f16(ap[k * 4], bp[k * 4], acc, 0, 0, 0);
#pragma unroll
            for (int r = 0; r < 4; r++)
                sm.wqp[w][(quad * 4 + r) * 16 + ln] = acc[r];
        }
        __syncthreads();
        if (tid < 512) {
            int pair = tid >> 8, e = tid & 255;
            int tau = 2 * bid + pair;
            int m0 = (tau & 15) * 16, n0 = (tau >> 4) * 16;
            float val = (sm.wqp[2 * pair][e] + sm.wqp[2 * pair + 1][e]) * SC2LOG2E;
            wq2[(size_t)(m0 + (e >> 4)) * 512 + n0 + (e & 15)] = val;
        }
        grid.sync();

        // ---------------- attn phase: b = bid
        {
            const float4* wqp4 = (const float4*)(wq2 + (size_t)bid * 512 + lane * 8);
            float4 w0 = wqp4[0], w1 = wqp4[1];
            const float4* vp4 = (const float4*)(vd + lane * 8);
            float4 vv0 = vp4[0], vv1 = vp4[1];
            float wr[8] = {w0.x, w0.y, w0.z, w0.w, w1.x, w1.y, w1.z, w1.w};
            float vr[8] = {vv0.x, vv0.y, vv0.z, vv0.w, vv1.x, vv1.y, vv1.z, vv1.w};

            const h8* up = (const h8*)(UH2 + (size_t)bid * 256 * 512) + lane;
#pragma unroll 2
            for (int i = 0; i < 16; i++) {
                int tp = w * 16 + i;
                h8 u = up[(size_t)tp * 64];
                float acc = 0.0f;
#pragma unroll
                for (int j = 0; j < 8; j++) {
                    float zz = wr[j] + (float)u[j];
                    float r = v_rcp(1.0f + v_exp2(zz));
                    acc = fmaf(vr[j], r, acc);
                }
#pragma unroll
                for (int o = 32; o; o >>= 1) acc += __shfl_xor(acc, o, 64);
                if (lane == 0) sm.at.es[tp] = -2.0f * acc;
            }
            __syncthreads();

            float v = 0.0f, ex = 0.0f;
            if (tid < 256) {
                v = sm.at.es[tid];
                float mx = v;
#pragma unroll
                for (int o = 32; o; o >>= 1) mx = fmaxf(mx, __shfl_xor(mx, o, 64));
                if (lane == 0) sm.at.red[w] = mx;
            }
            __syncthreads();
            float mall = fmaxf(fmaxf(sm.at.red[0], sm.at.red[1]),
                               fmaxf(sm.at.red[2], sm.at.red[3]));
            if (tid < 256) {
                ex = __expf(v - mall);
                float s = ex;
#pragma unroll
                for (int o = 32; o; o >>= 1) s += __shfl_xor(s, o, 64);
                if (lane == 0) sm.at.red2[w] = s;
            }
            __syncthreads();
            float tot = sm.at.red2[0] + sm.at.red2[1] + sm.at.red2[2] + sm.at.red2[3];
            float beta = 0.0f;
            if (tid < 256) beta = ex * v_rcp(tot);
            __syncthreads();
            if (tid < 256) {
                sm.at.es[tid] = beta;
                attn_out[(size_t)bid * 65536 + (size_t)t * 256 + tid] = beta;
            }
            __syncthreads();

            // c phase
            int tc = tid >> 7, g = tid & 127;
            float a0 = 0, a1 = 0, a2 = 0, a3 = 0;
            if (Hh) {
                const h4* hp = (const h4*)(Hh + ((size_t)bid * 256 + tc * 32) * 512) + g;
#pragma unroll 4
                for (int i = 0; i < 32; i++) {
                    h4 hv = hp[(size_t)i * 128];
                    float bt = sm.at.es[tc * 32 + i];
                    a0 = fmaf(bt, (float)hv[0], a0);
                    a1 = fmaf(bt, (float)hv[1], a1);
                    a2 = fmaf(bt, (float)hv[2], a2);
                    a3 = fmaf(bt, (float)hv[3], a3);
                }
            } else {
                const float4* hp = (const float4*)(Hf + ((size_t)bid * 256 + tc * 32) * 512) + g;
#pragma unroll 4
                for (int i = 0; i < 32; i++) {
                    float4 hv = hp[(size_t)i * 128];
                    float bt = sm.at.es[tc * 32 + i];
                    a0 = fmaf(bt, hv.x, a0);
                    a1 = fmaf(bt, hv.y, a1);
                    a2 = fmaf(bt, hv.z, a2);
                    a3 = fmaf(bt, hv.w, a3);
                }
            }
            *(float4*)&sm.at.part[tc][g * 4] = make_float4(a0, a1, a2, a3);
            __syncthreads();
            if (tid < 512) {
                int m = tid;
                float c = sm.at.part[0][m] + sm.at.part[1][m] + sm.at.part[2][m] + sm.at.part[3][m]
                        + sm.at.part[4][m] + sm.at.part[5][m] + sm.at.part[6][m] + sm.at.part[7][m];
                qcur[(size_t)bid * 1024 + m] = (_Float16)c;
                if (t == 255) out[(size_t)bid * 1024 + 512 + m] = c;
            }
        }
        grid.sync();

        // ---------------- gates phase: block tile (mb 64 x nb 32), 16 waves (4m x 2n x 2k)
        {
            int mb = bid & 3, nb = bid >> 2;
            int ms = w & 3, ns = (w >> 2) & 1, kh = w >> 3;
            int am0 = mb * 64 + ms * 16;
            int bn0 = nb * 32 + ns * 16;
            f4 acc = {0.f, 0.f, 0.f, 0.f};
            const h8* ap = (const h8*)(qcur + (size_t)(am0 + ln) * 1024) + kh * 64 + quad;
            const h8* bp = (const h8*)(Wg   + (size_t)(bn0 + ln) * 1024) + kh * 64 + quad;
#pragma unroll
            for (int k = 0; k < 16; k++)
                acc = __builtin_amdgcn_mfma_f32_16x16x32_f16(ap[k * 4], bp[k * 4], acc, 0, 0, 0);
#pragma unroll
            for (int r = 0; r < 4; r++)
                sm.gt[kh][ms * 16 + quad * 4 + r][ns * 16 + ln] = acc[r];
            __syncthreads();

            if (tid < 512) {
                int ml = tid >> 3, pl = tid & 7;
                int b = mb * 64 + ml, p = nb * 8 + pl;
                float4 gA = *(const float4*)&sm.gt[0][ml][pl * 4];
                float4 gB = *(const float4*)&sm.gt[1][ml][pl * 4];
                float4 bb = *(const float4*)(bsum + nb * 32 + pl * 4);
                float gi = gA.x + gB.x + bb.x;
                float gf = gA.y + gB.y + bb.y;
                float gg = gA.z + gB.z + bb.z;
                float go = gA.w + gB.w + bb.w;
                float ig = fast_sigmoid(gi);
                float fg = fast_sigmoid(gf);
                float g_ = fast_tanh(gg);
                float og = fast_sigmoid(go);
                float sold = sbuf[(size_t)b * 512 + p];
                float snew = fmaf(fg, sold, ig * g_);
                float dnew = og * fast_tanh(snew);
                sbuf[(size_t)b * 512 + p] = snew;
                qnxt[(size_t)b * 1024 + 512 + p] = (_Float16)dnew;
                ds[(size_t)b * 1024 + p]         = (_Float16)dnew;
                ds[(size_t)b * 1024 + 512 + p]   = (_Float16)snew;
                if (t == 255) out[(size_t)b * 1024 + p] = dnew;
            }
        }
        grid.sync();
    }
}

// ---------------------------------------------------------------------------
extern "C" void kernel_launch(void* const* d_in, const int* in_sizes, int n_in,
                              void* d_out, int out_size, void* d_ws, size_t ws_size,
                              hipStream_t stream) {
    const float* H   = (const float*)d_in[0];
    const float* d0  = (const float*)d_in[1];
    const float* s0  = (const float*)d_in[2];
    const float* Wd  = (const float*)d_in[3];
    const float* Ud  = (const float*)d_in[4];
    const float* vd  = (const float*)d_in[5];
    const float* Wih = (const float*)d_in[6];
    const float* Whh = (const float*)d_in[7];
    const float* bih = (const float*)d_in[8];
    const float* bhh = (const float*)d_in[9];

    float* out  = (float*)d_out;            // [B,1,1024]
    float* attn = out + 262144;             // [B,T,T]

    char* ws = (char*)d_ws;
    size_t off = 0;
    _Float16* UH2  = (_Float16*)(ws + off); off += 67108864;
    _Float16* Wdh  = (_Float16*)(ws + off); off += 1048576;
    _Float16* Wg   = (_Float16*)(ws + off); off += 4194304;
    float*    bsum = (float*)   (ws + off); off += 8192;
    float*    wq2  = (float*)   (ws + off); off += 524288;
    _Float16* qA   = (_Float16*)(ws + off); off += 524288;
    _Float16* qB   = (_Float16*)(ws + off); off += 524288;
    _Float16* ds   = (_Float16*)(ws + off); off += 524288;
    float*    sbuf = (float*)   (ws + off); off += 524288;
    _Float16* Hh   = nullptr;
    if (ws_size >= off + 67108864) { Hh = (_Float16*)(ws + off); off += 67108864; }

    convert_f16<<<512, 256, 0, stream>>>(Wd, Wdh, 524288);
    build_wg<<<2048, 256, 0, stream>>>(Wih, Whh, Wg);
    build_bsum<<<8, 256, 0, stream>>>(bih, bhh, bsum);
    if (Hh) convert_f16<<<32768, 256, 0, stream>>>(H, Hh, 33554432);
    init_state<<<512, 256, 0, stream>>>(d0, s0, sbuf, qA, ds);
    uh_mfma<<<1024, 128, 0, stream>>>(H, Ud, UH2);

    void* args[] = {(void*)&UH2, (void*)&Hh, (void*)&H, (void*)&vd,
                    (void*)&Wdh, (void*)&Wg, (void*)&bsum, (void*)&wq2,
                    (void*)&qA, (void*)&qB, (void*)&ds, (void*)&sbuf,
                    (void*)&attn, (void*)&out};
    hipLaunchCooperativeKernel((const void*)fused_loop, dim3(256), dim3(1024),
                               args, 0, stream);
}

// Round 7
// 34682.990 us; speedup vs baseline: 1.0203x; 1.0203x over previous
//
#include <hip/hip_runtime.h>
#include <hip/hip_fp16.h>

// Problem constants: B=256, T=256, M=512, P=512
typedef _Float16 h4 __attribute__((ext_vector_type(4)));
typedef _Float16 h8 __attribute__((ext_vector_type(8)));
typedef float    f4 __attribute__((ext_vector_type(4)));

#define SC2LOG2E 2.8853900817779268f   // 2 * log2(e)

// native exp2 / rcp (v_exp_f32 IS exp2)
__device__ __forceinline__ float v_exp2(float x) { float r; asm("v_exp_f32 %0, %1" : "=v"(r) : "v"(x)); return r; }
__device__ __forceinline__ float v_rcp (float x) { float r; asm("v_rcp_f32 %0, %1" : "=v"(r) : "v"(x)); return r; }
__device__ __forceinline__ float fast_tanh(float x) {
    float e = __expf(2.0f * x);
    return 1.0f - 2.0f * v_rcp(e + 1.0f);
}
__device__ __forceinline__ float fast_sigmoid(float x) {
    return v_rcp(1.0f + __expf(-x));
}

// Monotonic grid barrier: each block adds 1; wait until cnt >= target.
// Caller passes target = 256 * (barrier ordinal). No reset -> no race.
__device__ __forceinline__ void gbar(int* cnt, int target) {
    __syncthreads();
    if (threadIdx.x == 0) {
        __threadfence();   // make this block's writes agent-visible
        __hip_atomic_fetch_add(cnt, 1, __ATOMIC_ACQ_REL, __HIP_MEMORY_SCOPE_AGENT);
        while (__hip_atomic_load(cnt, __ATOMIC_ACQUIRE, __HIP_MEMORY_SCOPE_AGENT) < target)
            __builtin_amdgcn_s_sleep(1);
        __threadfence();   // invalidate local caches before reading others' data
    }
    __syncthreads();
}

// ---------------------------------------------------------------------------
__global__ void convert_f16(const float* __restrict__ s, _Float16* __restrict__ d, int n) {
    int i = (blockIdx.x * 256 + threadIdx.x) * 4;
    if (i < n) {
        float4 v = *(const float4*)(s + i);
        h4 o = {(_Float16)v.x, (_Float16)v.y, (_Float16)v.z, (_Float16)v.w};
        *(h4*)(d + i) = o;
    }
}

// ---------------------------------------------------------------------------
// Wg[(p<<2)|g][k] = f16( k<512 ? Wih[g*512+p][k] : Whh[g*512+p][k-512] )
__global__ void build_wg(const float* __restrict__ Wih, const float* __restrict__ Whh,
                         _Float16* __restrict__ Wg) {
    int idx = (blockIdx.x * 256 + threadIdx.x) * 4;    // over 2048*1024
    int np = idx >> 10, k = idx & 1023;
    int p = np >> 2, g = np & 3, row = g * 512 + p;
    const float* src = (k < 512) ? Wih + (size_t)row * 512 + k
                                 : Whh + (size_t)row * 512 + (k - 512);
    float4 v = *(const float4*)src;
    h4 o = {(_Float16)v.x, (_Float16)v.y, (_Float16)v.z, (_Float16)v.w};
    *(h4*)(Wg + idx) = o;
}

__global__ void build_bsum(const float* __restrict__ bih, const float* __restrict__ bhh,
                           float* __restrict__ bsum) {
    int np = blockIdx.x * 256 + threadIdx.x;  // 2048
    int p = np >> 2, g = np & 3, row = g * 512 + p;
    bsum[np] = bih[row] + bhh[row];
}

// ---------------------------------------------------------------------------
__global__ void init_state(const float* __restrict__ d0, const float* __restrict__ s0,
                           float* __restrict__ sbuf,
                           _Float16* __restrict__ qA, _Float16* __restrict__ ds,
                           int* __restrict__ bar) {
    int i = blockIdx.x * 256 + threadIdx.x;   // 512 x 256 = 131072
    if (i == 0) *bar = 0;
    float dv = d0[i], sv = s0[i];
    sbuf[i] = sv;
    int b = i >> 9, j = i & 511;
    qA[(size_t)b * 1024 + 512 + j] = (_Float16)dv;
    ds[(size_t)b * 1024 + j]       = (_Float16)dv;
    ds[(size_t)b * 1024 + 512 + j] = (_Float16)sv;
}

// ---------------------------------------------------------------------------
// UH2[r,n] = f16( 2log2e * sum_k H[r,k]*Ud[n,k] )  via MFMA, inline f32->f16.
// grid 1024 (m-tiles of 64), 128 threads (2 waves); n-loop inside (Ud L2-resident).
__global__ __launch_bounds__(128) void uh_mfma(const float* __restrict__ H,
                                               const float* __restrict__ Ud,
                                               _Float16* __restrict__ UH2) {
    int tid = threadIdx.x;
    int lane = tid & 63, w = tid >> 6;
    int ln = lane & 15, quad = lane >> 4;
    int m0 = blockIdx.x * 64;
    const float* arow = H + (size_t)(m0 + ln) * 512 + quad * 8;
    for (int n0 = 0; n0 < 512; n0 += 32) {
        f4 z = {0.f, 0.f, 0.f, 0.f};
        f4 acc[4] = {z, z, z, z};
        const float* brow = Ud + (size_t)(n0 + w * 16 + ln) * 512 + quad * 8;
#pragma unroll 2
        for (int k = 0; k < 16; k++) {
            float4 bx = *(const float4*)(brow + k * 32);
            float4 by = *(const float4*)(brow + k * 32 + 4);
            h8 b = {(_Float16)bx.x, (_Float16)bx.y, (_Float16)bx.z, (_Float16)bx.w,
                    (_Float16)by.x, (_Float16)by.y, (_Float16)by.z, (_Float16)by.w};
#pragma unroll
            for (int mt = 0; mt < 4; mt++) {
                const float* ap = arow + (size_t)mt * 16 * 512 + k * 32;
                float4 ax = *(const float4*)ap;
                float4 ay = *(const float4*)(ap + 4);
                h8 a = {(_Float16)ax.x, (_Float16)ax.y, (_Float16)ax.z, (_Float16)ax.w,
                        (_Float16)ay.x, (_Float16)ay.y, (_Float16)ay.z, (_Float16)ay.w};
                acc[mt] = __builtin_amdgcn_mfma_f32_16x16x32_f16(a, b, acc[mt], 0, 0, 0);
            }
        }
#pragma unroll
        for (int mt = 0; mt < 4; mt++)
#pragma unroll
            for (int r = 0; r < 4; r++)
                UH2[(size_t)(m0 + mt * 16 + quad * 4 + r) * 512 + n0 + w * 16 + ln] =
                    (_Float16)(acc[mt][r] * SC2LOG2E);
    }
}

// ---------------------------------------------------------------------------
// Persistent fused loop: 256 blocks x 1024 threads, cooperative launch,
// custom monotonic barrier between phases.
__global__ __launch_bounds__(1024, 4) void fused_loop(
        const _Float16* __restrict__ UH2, const _Float16* Hh,
        const float* __restrict__ Hf, const float* __restrict__ vd,
        const _Float16* __restrict__ Wdh, const _Float16* __restrict__ Wg,
        const float* __restrict__ bsum, float* wq2,
        _Float16* qA, _Float16* qB, _Float16* ds,
        float* __restrict__ sbuf, float* __restrict__ attn_out,
        float* __restrict__ out, int* bar) {
    __shared__ union {
        float wqp[8][256];
        struct { float es[256]; float red[4]; float red2[4]; float part[8][512]; } at;
        float gt[2][64][36];
    } sm;

    const int bid = blockIdx.x;
    const int tid = threadIdx.x;
    const int lane = tid & 63, w = tid >> 6;
    const int ln = lane & 15, quad = lane >> 4;
    int bt = 0;

    for (int t = 0; t < 256; ++t) {
        _Float16* qcur = (t & 1) ? qB : qA;
        _Float16* qnxt = (t & 1) ? qA : qB;

        // ---- wq phase: tiles 2*bid, 2*bid+1 (16x16, K=1024, 4-way k-split, 8 waves)
        if (w < 8) {
            int pair = w >> 2, kh = w & 3;
            int tau = 2 * bid + pair;
            int m0 = (tau & 15) * 16, n0 = (tau >> 4) * 16;
            f4 acc = {0.f, 0.f, 0.f, 0.f};
            const h8* ap = (const h8*)(ds  + (size_t)(m0 + ln) * 1024) + kh * 32 + quad;
            const h8* bp = (const h8*)(Wdh + (size_t)(n0 + ln) * 1024) + kh * 32 + quad;
#pragma unroll
            for (int k = 0; k < 8; k++)
                acc = __builtin_amdgcn_mfma_f32_16x16x32_f16(ap[k * 4], bp[k * 4], acc, 0, 0, 0);
#pragma unroll
            for (int r = 0; r < 4; r++)
                sm.wqp[w][(quad * 4 + r) * 16 + ln] = acc[r];
        }
        __syncthreads();
        if (tid < 512) {
            int pair = tid >> 8, e = tid & 255;
            int tau = 2 * bid + pair;
            int m0 = (tau & 15) * 16, n0 = (tau >> 4) * 16;
            float val = (sm.wqp[pair * 4][e] + sm.wqp[pair * 4 + 1][e] +
                         sm.wqp[pair * 4 + 2][e] + sm.wqp[pair * 4 + 3][e]) * SC2LOG2E;
            wq2[(size_t)(m0 + (e >> 4)) * 512 + n0 + (e & 15)] = val;
        }
        bt += 256; gbar(bar, bt);

        // ---- attn phase: b = bid
        {
            const float4* wqp4 = (const float4*)(wq2 + (size_t)bid * 512 + lane * 8);
            float4 w0 = wqp4[0], w1 = wqp4[1];
            const float4* vp4 = (const float4*)(vd + lane * 8);
            float4 vv0 = vp4[0], vv1 = vp4[1];
            float wr[8] = {w0.x, w0.y, w0.z, w0.w, w1.x, w1.y, w1.z, w1.w};
            float vr[8] = {vv0.x, vv0.y, vv0.z, vv0.w, vv1.x, vv1.y, vv1.z, vv1.w};

            // e phase: wave w owns rows [w*16, w*16+16), batched 4 rows for MLP
            const h8* up = (const h8*)(UH2 + (size_t)bid * 256 * 512) + lane;
#pragma unroll
            for (int i0 = 0; i0 < 16; i0 += 4) {
                int tp = w * 16 + i0;
                h8 u0 = up[(size_t)(tp + 0) * 64];
                h8 u1 = up[(size_t)(tp + 1) * 64];
                h8 u2 = up[(size_t)(tp + 2) * 64];
                h8 u3 = up[(size_t)(tp + 3) * 64];
                float ac0 = 0.f, ac1 = 0.f, ac2 = 0.f, ac3 = 0.f;
#pragma unroll
                for (int j = 0; j < 8; j++) {
                    ac0 = fmaf(vr[j], v_rcp(1.0f + v_exp2(wr[j] + (float)u0[j])), ac0);
                    ac1 = fmaf(vr[j], v_rcp(1.0f + v_exp2(wr[j] + (float)u1[j])), ac1);
                    ac2 = fmaf(vr[j], v_rcp(1.0f + v_exp2(wr[j] + (float)u2[j])), ac2);
                    ac3 = fmaf(vr[j], v_rcp(1.0f + v_exp2(wr[j] + (float)u3[j])), ac3);
                }
#pragma unroll
                for (int o = 32; o; o >>= 1) {
                    ac0 += __shfl_xor(ac0, o, 64);
                    ac1 += __shfl_xor(ac1, o, 64);
                    ac2 += __shfl_xor(ac2, o, 64);
                    ac3 += __shfl_xor(ac3, o, 64);
                }
                if (lane == 0) {
                    sm.at.es[tp + 0] = -2.0f * ac0;
                    sm.at.es[tp + 1] = -2.0f * ac1;
                    sm.at.es[tp + 2] = -2.0f * ac2;
                    sm.at.es[tp + 3] = -2.0f * ac3;
                }
            }
            __syncthreads();

            float v = 0.0f, ex = 0.0f;
            if (tid < 256) {
                v = sm.at.es[tid];
                float mx = v;
#pragma unroll
                for (int o = 32; o; o >>= 1) mx = fmaxf(mx, __shfl_xor(mx, o, 64));
                if (lane == 0) sm.at.red[w] = mx;
            }
            __syncthreads();
            float mall = fmaxf(fmaxf(sm.at.red[0], sm.at.red[1]),
                               fmaxf(sm.at.red[2], sm.at.red[3]));
            if (tid < 256) {
                ex = __expf(v - mall);
                float s = ex;
#pragma unroll
                for (int o = 32; o; o >>= 1) s += __shfl_xor(s, o, 64);
                if (lane == 0) sm.at.red2[w] = s;
            }
            __syncthreads();
            float tot = sm.at.red2[0] + sm.at.red2[1] + sm.at.red2[2] + sm.at.red2[3];
            float beta = 0.0f;
            if (tid < 256) beta = ex * v_rcp(tot);
            __syncthreads();
            if (tid < 256) {
                sm.at.es[tid] = beta;
                attn_out[(size_t)bid * 65536 + (size_t)t * 256 + tid] = beta;
            }
            __syncthreads();

            // c phase
            int tc = tid >> 7, g = tid & 127;
            float a0 = 0, a1 = 0, a2 = 0, a3 = 0;
            if (Hh) {
                const h4* hp = (const h4*)(Hh + ((size_t)bid * 256 + tc * 32) * 512) + g;
#pragma unroll 4
                for (int i = 0; i < 32; i++) {
                    h4 hv = hp[(size_t)i * 128];
                    float bt2 = sm.at.es[tc * 32 + i];
                    a0 = fmaf(bt2, (float)hv[0], a0);
                    a1 = fmaf(bt2, (float)hv[1], a1);
                    a2 = fmaf(bt2, (float)hv[2], a2);
                    a3 = fmaf(bt2, (float)hv[3], a3);
                }
            } else {
                const float4* hp = (const float4*)(Hf + ((size_t)bid * 256 + tc * 32) * 512) + g;
#pragma unroll 4
                for (int i = 0; i < 32; i++) {
                    float4 hv = hp[(size_t)i * 128];
                    float bt2 = sm.at.es[tc * 32 + i];
                    a0 = fmaf(bt2, hv.x, a0);
                    a1 = fmaf(bt2, hv.y, a1);
                    a2 = fmaf(bt2, hv.z, a2);
                    a3 = fmaf(bt2, hv.w, a3);
                }
            }
            *(float4*)&sm.at.part[tc][g * 4] = make_float4(a0, a1, a2, a3);
            __syncthreads();
            if (tid < 512) {
                int m = tid;
                float c = sm.at.part[0][m] + sm.at.part[1][m] + sm.at.part[2][m] + sm.at.part[3][m]
                        + sm.at.part[4][m] + sm.at.part[5][m] + sm.at.part[6][m] + sm.at.part[7][m];
                qcur[(size_t)bid * 1024 + m] = (_Float16)c;
                if (t == 255) out[(size_t)bid * 1024 + 512 + m] = c;
            }
        }
        bt += 256; gbar(bar, bt);

        // ---- gates phase: block tile (mb 64 x nb 32), 16 waves (4m x 2n x 2k)
        {
            int mb = bid & 3, nb = bid >> 2;
            int ms = w & 3, ns = (w >> 2) & 1, kh = w >> 3;
            int am0 = mb * 64 + ms * 16;
            int bn0 = nb * 32 + ns * 16;
            f4 acc = {0.f, 0.f, 0.f, 0.f};
            const h8* ap = (const h8*)(qcur + (size_t)(am0 + ln) * 1024) + kh * 64 + quad;
            const h8* bp = (const h8*)(Wg   + (size_t)(bn0 + ln) * 1024) + kh * 64 + quad;
#pragma unroll
            for (int k = 0; k < 16; k++)
                acc = __builtin_amdgcn_mfma_f32_16x16x32_f16(ap[k * 4], bp[k * 4], acc, 0, 0, 0);
#pragma unroll
            for (int r = 0; r < 4; r++)
                sm.gt[kh][ms * 16 + quad * 4 + r][ns * 16 + ln] = acc[r];
            __syncthreads();

            if (tid < 512) {
                int ml = tid >> 3, pl = tid & 7;
                int b = mb * 64 + ml, p = nb * 8 + pl;
                float4 gA = *(const float4*)&sm.gt[0][ml][pl * 4];
                float4 gB = *(const float4*)&sm.gt[1][ml][pl * 4];
                float4 bb = *(const float4*)(bsum + nb * 32 + pl * 4);
                float gi = gA.x + gB.x + bb.x;
                float gf = gA.y + gB.y + bb.y;
                float gg = gA.z + gB.z + bb.z;
                float go = gA.w + gB.w + bb.w;
                float ig = fast_sigmoid(gi);
                float fg = fast_sigmoid(gf);
                float g_ = fast_tanh(gg);
                float og = fast_sigmoid(go);
                float sold = sbuf[(size_t)b * 512 + p];
                float snew = fmaf(fg, sold, ig * g_);
                float dnew = og * fast_tanh(snew);
                sbuf[(size_t)b * 512 + p] = snew;
                qnxt[(size_t)b * 1024 + 512 + p] = (_Float16)dnew;
                ds[(size_t)b * 1024 + p]         = (_Float16)dnew;
                ds[(size_t)b * 1024 + 512 + p]   = (_Float16)snew;
                if (t == 255) out[(size_t)b * 1024 + p] = dnew;
            }
        }
        bt += 256; gbar(bar, bt);
    }
}

// ---------------------------------------------------------------------------
extern "C" void kernel_launch(void* const* d_in, const int* in_sizes, int n_in,
                              void* d_out, int out_size, void* d_ws, size_t ws_size,
                              hipStream_t stream) {
    const float* H   = (const float*)d_in[0];
    const float* d0  = (const float*)d_in[1];
    const float* s0  = (const float*)d_in[2];
    const float* Wd  = (const float*)d_in[3];
    const float* Ud  = (const float*)d_in[4];
    const float* vd  = (const float*)d_in[5];
    const float* Wih = (const float*)d_in[6];
    const float* Whh = (const float*)d_in[7];
    const float* bih = (const float*)d_in[8];
    const float* bhh = (const float*)d_in[9];

    float* out  = (float*)d_out;            // [B,1,1024]
    float* attn = out + 262144;             // [B,T,T]

    char* ws = (char*)d_ws;
    size_t off = 0;
    _Float16* UH2  = (_Float16*)(ws + off); off += 67108864;
    _Float16* Wdh  = (_Float16*)(ws + off); off += 1048576;
    _Float16* Wg   = (_Float16*)(ws + off); off += 4194304;
    float*    bsum = (float*)   (ws + off); off += 8192;
    float*    wq2  = (float*)   (ws + off); off += 524288;
    _Float16* qA   = (_Float16*)(ws + off); off += 524288;
    _Float16* qB   = (_Float16*)(ws + off); off += 524288;
    _Float16* ds   = (_Float16*)(ws + off); off += 524288;
    float*    sbuf = (float*)   (ws + off); off += 524288;
    int*      bar  = (int*)     (ws + off); off += 4096;
    _Float16* Hh   = nullptr;
    if (ws_size >= off + 67108864) { Hh = (_Float16*)(ws + off); off += 67108864; }

    convert_f16<<<512, 256, 0, stream>>>(Wd, Wdh, 524288);
    build_wg<<<2048, 256, 0, stream>>>(Wih, Whh, Wg);
    build_bsum<<<8, 256, 0, stream>>>(bih, bhh, bsum);
    if (Hh) convert_f16<<<32768, 256, 0, stream>>>(H, Hh, 33554432);
    init_state<<<512, 256, 0, stream>>>(d0, s0, sbuf, qA, ds, bar);
    uh_mfma<<<1024, 128, 0, stream>>>(H, Ud, UH2);

    void* args[] = {(void*)&UH2, (void*)&Hh, (void*)&H, (void*)&vd,
                    (void*)&Wdh, (void*)&Wg, (void*)&bsum, (void*)&wq2,
                    (void*)&qA, (void*)&qB, (void*)&ds, (void*)&sbuf,
                    (void*)&attn, (void*)&out, (void*)&bar};
    hipLaunchCooperativeKernel((const void*)fused_loop, dim3(256), dim3(1024),
                               args, 0, stream);
}